// Round 4
// baseline (122.979 us; speedup 1.0000x reference)
//
#include <hip/hip_runtime.h>
#include <hip/hip_cooperative_groups.h>

namespace cg = cooperative_groups;

// Problem constants (reference: B=8, E=16, H=256, W=256)
#define NB 8
#define NE 16
#define HW (256 * 256)        // pixels per sample = 65536
#define HW4 (HW / 4)          // float4 groups per sample = 16384
#define NPIX (NB * HW)        // total pixels = 524288
#define NT4 (NPIX / 4)        // total float4 pixel-groups = 131072
#define NBLK 512              // grid (NT4 / 256); 2 blocks/CU -> co-resident

// val(pixel) = mean_e |f_e - o| - 0.5 * mean_{e,e'} |f_e - f_e'|
//            = (1/16) * S1 - (1/256) * S2   (S2 = unordered-pair sum)
// out = (1/NPIX) * sum over pixels of val
//
// Single cooperative kernel: per-block partials to d_ws, grid.sync(),
// block 0 reduces the 512 partials. Saves the second dispatch + its
// 512-float latency round-trip vs the R3 two-kernel version.

__global__ __launch_bounds__(256) void crps_fused_kernel(
    const float* __restrict__ fore,   // [B, E, HW]
    const float* __restrict__ obs,    // [B, HW]
    float* __restrict__ partial,      // [NBLK] scratch (d_ws)
    float* __restrict__ out)          // [1]
{
    const int idx = blockIdx.x * blockDim.x + threadIdx.x;   // 0 .. NT4-1
    const int b  = idx >> 14;          // idx / HW4
    const int p4 = idx & (HW4 - 1);

    const float4* fore4 = reinterpret_cast<const float4*>(fore);
    const float4* obs4  = reinterpret_cast<const float4*>(obs);

    // 16 ensemble members, 16B/lane coalesced loads (1KB per wave-instr).
    // All 17 loads issue before first use; 8 waves/CU gives ~136KB/CU in
    // flight vs ~23KB needed to saturate HBM at 900cyc latency.
    float v[NE][4];
#pragma unroll
    for (int e = 0; e < NE; ++e) {
        float4 t = fore4[(size_t)(b * NE + e) * HW4 + p4];
        v[e][0] = t.x; v[e][1] = t.y; v[e][2] = t.z; v[e][3] = t.w;
    }
    float4 ot = obs4[(size_t)b * HW4 + p4];
    float o[4] = { ot.x, ot.y, ot.z, ot.w };

    // 4 components independent -> 4-way ILP on the add chains.
    float acc = 0.0f;
#pragma unroll
    for (int c = 0; c < 4; ++c) {
        float s1 = 0.0f;
#pragma unroll
        for (int e = 0; e < NE; ++e)
            s1 += fabsf(v[e][c] - o[c]);
        float s2 = 0.0f;
#pragma unroll
        for (int i = 0; i < NE; ++i)
#pragma unroll
            for (int j = i + 1; j < NE; ++j)
                s2 += fabsf(v[i][c] - v[j][c]);
        acc += s1 * (1.0f / NE) - s2 * (1.0f / (NE * NE));
    }

    // Wave (64-lane) shuffle reduction
#pragma unroll
    for (int off = 32; off > 0; off >>= 1)
        acc += __shfl_down(acc, off);

    __shared__ float smem[4];          // 256 threads = 4 waves
    const int lane = threadIdx.x & 63;
    const int wave = threadIdx.x >> 6;
    if (lane == 0) smem[wave] = acc;
    __syncthreads();
    if (threadIdx.x == 0)
        partial[blockIdx.x] = smem[0] + smem[1] + smem[2] + smem[3];

    // Grid-wide barrier (device-scope release/acquire across XCDs), then
    // block 0 folds the 512 partials.
    cg::this_grid().sync();

    if (blockIdx.x == 0) {
        const int t = threadIdx.x;
        float a2 = partial[t] + partial[t + 256];
#pragma unroll
        for (int off = 32; off > 0; off >>= 1)
            a2 += __shfl_down(a2, off);
        __shared__ float smem2[4];
        if (lane == 0) smem2[wave] = a2;
        __syncthreads();
        if (t == 0)
            out[0] = (smem2[0] + smem2[1] + smem2[2] + smem2[3]) * (1.0f / NPIX);
    }
}

extern "C" void kernel_launch(void* const* d_in, const int* in_sizes, int n_in,
                              void* d_out, int out_size, void* d_ws, size_t ws_size,
                              hipStream_t stream) {
    const float* fore = (const float*)d_in[0];   // [8,16,256,256] f32
    const float* obs  = (const float*)d_in[1];   // [8,256,256] f32
    float* out     = (float*)d_out;
    float* partial = (float*)d_ws;               // 512 floats of scratch

    void* args[] = { (void*)&fore, (void*)&obs, (void*)&partial, (void*)&out };
    hipLaunchCooperativeKernel((const void*)crps_fused_kernel,
                               dim3(NBLK), dim3(256), args, 0, stream);
}

// Round 5
// 78.057 us; speedup vs baseline: 1.5755x; 1.5755x over previous
//
#include <hip/hip_runtime.h>

// Problem constants (reference: B=8, E=16, H=256, W=256)
#define NB 8
#define NE 16
#define HW (256 * 256)        // pixels per sample = 65536
#define HW4 (HW / 4)          // float4 groups per sample = 16384
#define NPIX (NB * HW)        // total pixels = 524288
#define NT4 (NPIX / 4)        // total float4 pixel-groups = 131072
#define NBLK 512              // K1 grid (NT4 / 256)

// val(pixel) = mean_e |f_e - o| - 0.5 * mean_{e,e'} |f_e - f_e'|
//            = (1/16) * S1 - (1/256) * S2   (S2 = unordered-pair sum)
// out = (1/NPIX) * sum over pixels of val
//
// R4 post-mortem: hipLaunchCooperativeKernel costs ~45us/replay inside graph
// capture (123 vs 77 us) — plain two-kernel reduction is the right structure.
// K1: one float4-pixel-group per thread, plain per-block partial to d_ws.
// K2: one 64-lane wave folds the 512 partials (no LDS, no barrier).

__global__ __launch_bounds__(256) void crps_partial_kernel(
    const float* __restrict__ fore,   // [B, E, HW]
    const float* __restrict__ obs,    // [B, HW]
    float* __restrict__ partial)      // [NBLK]
{
    const int idx = blockIdx.x * blockDim.x + threadIdx.x;   // 0 .. NT4-1
    const int b  = idx >> 14;          // idx / HW4
    const int p4 = idx & (HW4 - 1);

    const float4* fore4 = reinterpret_cast<const float4*>(fore);
    const float4* obs4  = reinterpret_cast<const float4*>(obs);

    // 16 ensemble members, 16B/lane coalesced loads (1KB per wave-instr).
    // All 17 loads issue before first use; 8 waves/CU gives ~136KB/CU in
    // flight vs ~23KB needed to cover ~900cyc HBM latency at stream rate.
    float v[NE][4];
#pragma unroll
    for (int e = 0; e < NE; ++e) {
        float4 t = fore4[(size_t)(b * NE + e) * HW4 + p4];
        v[e][0] = t.x; v[e][1] = t.y; v[e][2] = t.z; v[e][3] = t.w;
    }
    float4 ot = obs4[(size_t)b * HW4 + p4];
    float o[4] = { ot.x, ot.y, ot.z, ot.w };

    // 4 components independent -> 4-way ILP on the add chains.
    float acc = 0.0f;
#pragma unroll
    for (int c = 0; c < 4; ++c) {
        float s1 = 0.0f;
#pragma unroll
        for (int e = 0; e < NE; ++e)
            s1 += fabsf(v[e][c] - o[c]);
        float s2 = 0.0f;
#pragma unroll
        for (int i = 0; i < NE; ++i)
#pragma unroll
            for (int j = i + 1; j < NE; ++j)
                s2 += fabsf(v[i][c] - v[j][c]);
        acc += s1 * (1.0f / NE) - s2 * (1.0f / (NE * NE));
    }

    // Wave (64-lane) shuffle reduction
#pragma unroll
    for (int off = 32; off > 0; off >>= 1)
        acc += __shfl_down(acc, off);

    __shared__ float smem[4];          // 256 threads = 4 waves
    const int lane = threadIdx.x & 63;
    const int wave = threadIdx.x >> 6;
    if (lane == 0) smem[wave] = acc;
    __syncthreads();
    if (threadIdx.x == 0)
        partial[blockIdx.x] = smem[0] + smem[1] + smem[2] + smem[3];
}

__global__ __launch_bounds__(64) void crps_final_kernel(
    const float* __restrict__ partial,  // [NBLK]
    float* __restrict__ out)            // [1]
{
    const int t = threadIdx.x;          // 0..63, single wave
    const float4* p4 = reinterpret_cast<const float4*>(partial);
    float4 a = p4[t];                   // partials 4t .. 4t+3
    float4 b = p4[t + 64];              // partials 256+4t ..
    float acc = (a.x + a.y) + (a.z + a.w) + (b.x + b.y) + (b.z + b.w);

#pragma unroll
    for (int off = 32; off > 0; off >>= 1)
        acc += __shfl_down(acc, off);

    if (t == 0)
        out[0] = acc * (1.0f / NPIX);
}

extern "C" void kernel_launch(void* const* d_in, const int* in_sizes, int n_in,
                              void* d_out, int out_size, void* d_ws, size_t ws_size,
                              hipStream_t stream) {
    const float* fore = (const float*)d_in[0];   // [8,16,256,256] f32
    const float* obs  = (const float*)d_in[1];   // [8,256,256] f32
    float* out     = (float*)d_out;
    float* partial = (float*)d_ws;               // 512 floats of scratch

    crps_partial_kernel<<<NBLK, 256, 0, stream>>>(fore, obs, partial);
    crps_final_kernel<<<1, 64, 0, stream>>>(partial, out);
}